// Round 1
// baseline (220.353 us; speedup 1.0000x reference)
//
#include <hip/hip_runtime.h>
#include <hip/hip_bf16.h>
#include <cstdint>

typedef uint16_t u16;
typedef __attribute__((ext_vector_type(8))) short short8;
typedef __attribute__((ext_vector_type(4))) float f32x4;

static constexpr int S = 4096;
static constexpr int D2 = 512;
static constexpr size_t RET_ELEMS = 16384ull * 512ull;      // 8,388,608 floats
static constexpr float SCALE = 0.04419417382415922f;        // 512^-0.5

__device__ __forceinline__ u16 f2bf(float f) {
  uint32_t u = __float_as_uint(f);
  u += 0x7fffu + ((u >> 16) & 1u);
  return (u16)(u >> 16);
}

__device__ __forceinline__ void unpack8(const uint4& r, float* v) {
  v[0] = __uint_as_float(r.x << 16);
  v[1] = __uint_as_float(r.x & 0xffff0000u);
  v[2] = __uint_as_float(r.y << 16);
  v[3] = __uint_as_float(r.y & 0xffff0000u);
  v[4] = __uint_as_float(r.z << 16);
  v[5] = __uint_as_float(r.z & 0xffff0000u);
  v[6] = __uint_as_float(r.w << 16);
  v[7] = __uint_as_float(r.w & 0xffff0000u);
}

// ---------------- f32 -> bf16 cast ----------------
__global__ void cast_f32_bf16(const float* __restrict__ src, u16* __restrict__ dst, int n4) {
  int idx = blockIdx.x * blockDim.x + threadIdx.x;
  if (idx < n4) {
    float4 v = *(const float4*)(src + (size_t)idx * 4);
    ushort4 o;
    o.x = f2bf(v.x); o.y = f2bf(v.y); o.z = f2bf(v.z); o.w = f2bf(v.w);
    *(ushort4*)(dst + (size_t)idx * 4) = o;
  }
}

// ---------------- Q/K projection GEMM ----------------
// C[m,n] = sum_k Xb[m,k] * Wb[n,k]   (x @ W^T), bf16 in, bf16 out, f32 accum
// tile 128x128, BK=32, 256 threads = 4 waves (2x2), each wave 64x64 = 4x4 frags
#define BM 128
#define BN 128
#define BK 32
#define LDSP 40   // padded LDS row stride (bf16 elems): 80B -> spreads banks

__global__ __launch_bounds__(256) void qk_gemm(
    const u16* __restrict__ Xb, const u16* __restrict__ Wqb, const u16* __restrict__ Wkb,
    u16* __restrict__ Qb, u16* __restrict__ Kb) {
  __shared__ u16 Xs[BM * LDSP];
  __shared__ u16 Ws[BN * LDSP];
  const int m0 = blockIdx.x * BM;
  const int sel = blockIdx.y >> 2;
  const int n0 = (blockIdx.y & 3) * BN;
  const u16* __restrict__ Wb = sel ? Wkb : Wqb;
  u16* __restrict__ Cb = sel ? Kb : Qb;

  const int t = threadIdx.x;
  const int lane = t & 63, w = t >> 6;
  const int wm = w >> 1, wn = w & 1;
  const int r16 = lane & 15, kg = lane >> 4;
  const int srow = t >> 2, skcol = (t & 3) * 8;

  f32x4 acc[4][4] = {};

  for (int kt = 0; kt < D2; kt += BK) {
    __syncthreads();
    // stage A and B tiles (reg-staged, padded LDS)
    for (int p = 0; p < 2; ++p) {
      int row = srow + p * 64;
      uint4 va = *(const uint4*)(Xb + (size_t)(m0 + row) * D2 + kt + skcol);
      *(uint4*)(Xs + row * LDSP + skcol) = va;
      uint4 vb = *(const uint4*)(Wb + (size_t)(n0 + row) * D2 + kt + skcol);
      *(uint4*)(Ws + row * LDSP + skcol) = vb;
    }
    __syncthreads();
    short8 a[4], b[4];
    for (int f = 0; f < 4; ++f) {
      a[f] = *(const short8*)(Xs + (wm * 64 + f * 16 + r16) * LDSP + kg * 8);
      b[f] = *(const short8*)(Ws + (wn * 64 + f * 16 + r16) * LDSP + kg * 8);
    }
    for (int fm = 0; fm < 4; ++fm)
      for (int fn = 0; fn < 4; ++fn)
        acc[fm][fn] = __builtin_amdgcn_mfma_f32_16x16x32_bf16(a[fm], b[fn], acc[fm][fn], 0, 0, 0);
  }

  // C/D layout (m89-verified): col = lane&15, row = (lane>>4)*4 + r
  for (int fm = 0; fm < 4; ++fm) {
    int grow = m0 + wm * 64 + fm * 16 + kg * 4;
    for (int fn = 0; fn < 4; ++fn) {
      int gcol = n0 + wn * 64 + fn * 16 + r16;
      for (int r = 0; r < 4; ++r)
        Cb[(size_t)(grow + r) * D2 + gcol] = f2bf(acc[fm][fn][r]);
    }
  }
}

// ---------------- fused banded attention ----------------
// one wave per query row. window j in [i-64, i-1].
__global__ __launch_bounds__(256) void attn_kernel(
    const u16* __restrict__ Qb, const u16* __restrict__ Kb, const u16* __restrict__ Xb,
    float* __restrict__ out) {
  __shared__ float plds[4][64];
  const int w = threadIdx.x >> 6, lane = threadIdx.x & 63;
  const int q = blockIdx.x * 4 + w;          // 0..16383
  const int b = q >> 12, i = q & (S - 1);
  const int jbase = i - 64;

  // load Q row fragment (8 bf16 per lane, coalesced)
  float qv[8];
  {
    uint4 qr = *(const uint4*)(Qb + (size_t)q * D2 + lane * 8);
    unpack8(qr, qv);
  }

  // scores: cooperative 64-lane dot per key j
  float s = -INFINITY;
  for (int jo = 0; jo < 64; ++jo) {
    int j = jbase + jo;
    if (j >= 0) {                             // wave-uniform branch
      uint4 kr = *(const uint4*)(Kb + ((size_t)(b << 12) + j) * D2 + lane * 8);
      float kv[8]; unpack8(kr, kv);
      float part = 0.f;
      #pragma unroll
      for (int d = 0; d < 8; ++d) part += qv[d] * kv[d];
      #pragma unroll
      for (int off = 32; off; off >>= 1) part += __shfl_xor(part, off);
      if (lane == jo) s = part * SCALE;
    }
  }

  // wave softmax over 64 lanes
  float m = s;
  #pragma unroll
  for (int off = 32; off; off >>= 1) m = fmaxf(m, __shfl_xor(m, off));
  float e = (s == -INFINITY) ? 0.f : __expf(s - m);
  float sum = e;
  #pragma unroll
  for (int off = 32; off; off >>= 1) sum += __shfl_xor(sum, off);
  float p = (sum > 0.f) ? e / sum : 0.f;
  plds[w][lane] = p;
  __syncthreads();

  // full attn row write: zeros + band fused (no separate memset pass)
  float* arow = out + RET_ELEMS + (size_t)q * S;
  for (int t2 = 0; t2 < 16; ++t2) {
    int c0 = t2 * 256 + lane * 4;
    float4 v;
    #pragma unroll
    for (int c = 0; c < 4; ++c) {
      int cc = c0 + c;
      int wo = cc - jbase;                    // band slot
      float pv = (wo >= 0 && wo < 64) ? plds[w][wo] : 0.f;
      ((float*)&v)[c] = pv;
    }
    *(float4*)(arow + c0) = v;
  }

  // retrieved = P @ X  (f32 accum, bf16 X)
  float acc[8] = {0.f, 0.f, 0.f, 0.f, 0.f, 0.f, 0.f, 0.f};
  for (int jo = 0; jo < 64; ++jo) {
    int j = jbase + jo;
    if (j >= 0) {
      float pj = plds[w][jo];
      uint4 xr = *(const uint4*)(Xb + ((size_t)(b << 12) + j) * D2 + lane * 8);
      float xv[8]; unpack8(xr, xv);
      #pragma unroll
      for (int d = 0; d < 8; ++d) acc[d] += pj * xv[d];
    }
  }
  float* rrow = out + (size_t)q * D2 + lane * 8;
  float4 r0 = {acc[0], acc[1], acc[2], acc[3]};
  float4 r1 = {acc[4], acc[5], acc[6], acc[7]};
  *(float4*)(rrow) = r0;
  *(float4*)(rrow + 4) = r1;
}

extern "C" void kernel_launch(void* const* d_in, const int* in_sizes, int n_in,
                              void* d_out, int out_size, void* d_ws, size_t ws_size,
                              hipStream_t stream) {
  const float* states = (const float*)d_in[0];   // [4,4096,256,2] f32 = 8,388,608
  const float* W_q    = (const float*)d_in[1];   // [512,512]
  const float* W_k    = (const float*)d_in[2];   // [512,512]
  float* out = (float*)d_out;                    // [retrieved | attn] f32

  char* ws = (char*)d_ws;
  u16* Xb  = (u16*)(ws);                         // 16,777,216 B
  u16* Qb  = (u16*)(ws + 16777216);              // 16,777,216 B
  u16* Kb  = (u16*)(ws + 33554432);              // 16,777,216 B
  u16* Wqb = (u16*)(ws + 50331648);              // 524,288 B
  u16* Wkb = (u16*)(ws + 50855936);              // 524,288 B

  // casts: n/4 threads each
  cast_f32_bf16<<<8192, 256, 0, stream>>>(states, Xb, 2097152);
  cast_f32_bf16<<<256, 256, 0, stream>>>(W_q, Wqb, 65536);
  cast_f32_bf16<<<256, 256, 0, stream>>>(W_k, Wkb, 65536);

  // Q and K projections: grid.y 0..3 -> Q tiles, 4..7 -> K tiles
  qk_gemm<<<dim3(128, 8), 256, 0, stream>>>(Xb, Wqb, Wkb, Qb, Kb);

  // fused banded attention, one wave per query
  attn_kernel<<<4096, 256, 0, stream>>>(Qb, Kb, Xb, out);
}

// Round 3
// 173.890 us; speedup vs baseline: 1.2672x; 1.2672x over previous
//
#include <hip/hip_runtime.h>
#include <hip/hip_bf16.h>
#include <cstdint>

typedef uint16_t u16;
typedef __attribute__((ext_vector_type(8))) short short8;
typedef __attribute__((ext_vector_type(4))) float f32x4;
typedef __attribute__((ext_vector_type(2))) float f32x2;
typedef __attribute__((ext_vector_type(4))) float fv4;   // native vec for nontemporal stores

static constexpr int S = 4096;
static constexpr int D2 = 512;
static constexpr size_t RET_ELEMS = 16384ull * 512ull;      // 8,388,608 floats
static constexpr float SCALE = 0.04419417382415922f;        // 512^-0.5

__device__ __forceinline__ u16 f2bf(float f) {
  uint32_t u = __float_as_uint(f);
  u += 0x7fffu + ((u >> 16) & 1u);
  return (u16)(u >> 16);
}

__device__ __forceinline__ float bflo(uint32_t u) { return __uint_as_float(u << 16); }
__device__ __forceinline__ float bfhi(uint32_t u) { return __uint_as_float(u & 0xffff0000u); }

// ---------------- f32 -> bf16 cast ----------------
__global__ void cast_f32_bf16(const float* __restrict__ src, u16* __restrict__ dst, int n4) {
  int idx = blockIdx.x * blockDim.x + threadIdx.x;
  if (idx < n4) {
    float4 v = *(const float4*)(src + (size_t)idx * 4);
    ushort4 o;
    o.x = f2bf(v.x); o.y = f2bf(v.y); o.z = f2bf(v.z); o.w = f2bf(v.w);
    *(ushort4*)(dst + (size_t)idx * 4) = o;
  }
}

// ---------------- Q/K projection GEMM ----------------
#define BM 128
#define BN 128
#define BK 32
#define LDSP 40

__global__ __launch_bounds__(256) void qk_gemm(
    const u16* __restrict__ Xb, const u16* __restrict__ Wqb, const u16* __restrict__ Wkb,
    u16* __restrict__ Qb, u16* __restrict__ Kb) {
  __shared__ u16 Xs[BM * LDSP];
  __shared__ u16 Ws[BN * LDSP];
  const int m0 = blockIdx.x * BM;
  const int sel = blockIdx.y >> 2;
  const int n0 = (blockIdx.y & 3) * BN;
  const u16* __restrict__ Wb = sel ? Wkb : Wqb;
  u16* __restrict__ Cb = sel ? Kb : Qb;

  const int t = threadIdx.x;
  const int lane = t & 63, w = t >> 6;
  const int wm = w >> 1, wn = w & 1;
  const int r16 = lane & 15, kg = lane >> 4;
  const int srow = t >> 2, skcol = (t & 3) * 8;

  f32x4 acc[4][4] = {};

  for (int kt = 0; kt < D2; kt += BK) {
    __syncthreads();
    for (int p = 0; p < 2; ++p) {
      int row = srow + p * 64;
      uint4 va = *(const uint4*)(Xb + (size_t)(m0 + row) * D2 + kt + skcol);
      *(uint4*)(Xs + row * LDSP + skcol) = va;
      uint4 vb = *(const uint4*)(Wb + (size_t)(n0 + row) * D2 + kt + skcol);
      *(uint4*)(Ws + row * LDSP + skcol) = vb;
    }
    __syncthreads();
    short8 a[4], b[4];
    for (int f = 0; f < 4; ++f) {
      a[f] = *(const short8*)(Xs + (wm * 64 + f * 16 + r16) * LDSP + kg * 8);
      b[f] = *(const short8*)(Ws + (wn * 64 + f * 16 + r16) * LDSP + kg * 8);
    }
    for (int fm = 0; fm < 4; ++fm)
      for (int fn = 0; fn < 4; ++fn)
        acc[fm][fn] = __builtin_amdgcn_mfma_f32_16x16x32_bf16(a[fm], b[fn], acc[fm][fn], 0, 0, 0);
  }

  for (int fm = 0; fm < 4; ++fm) {
    int grow = m0 + wm * 64 + fm * 16 + kg * 4;
    for (int fn = 0; fn < 4; ++fn) {
      int gcol = n0 + wn * 64 + fn * 16 + r16;
      for (int r = 0; r < 4; ++r)
        Cb[(size_t)(grow + r) * D2 + gcol] = f2bf(acc[fm][fn][r]);
    }
  }
}

// ---------------- fused banded attention (MFMA scores) ----------------
// 256 blocks x 256 threads. Block = 64 consecutive queries; wave = 16 queries.
// Window for wave's queries [qg, qg+15]: keys [qg-64, qg+15) -> 5 blocks of 16.
__global__ __launch_bounds__(256) void attn_kernel(
    const u16* __restrict__ Qb, const u16* __restrict__ Kb, const u16* __restrict__ Xb,
    float* __restrict__ out) {
  __shared__ float p_jm[4][80][16];   // [wave][band col][query m] -> PV broadcast reads
  __shared__ float p_mj[4][16][85];   // [wave][query m][band col] -> band row writes

  const int bid = blockIdx.x;
  const int swz = (bid & 7) * 32 + (bid >> 3);   // XCD-bijective: 32 contiguous blocks/XCD
  const int w = threadIdx.x >> 6;
  const int lane = threadIdx.x & 63;
  const int qg = swz * 64 + w * 16;              // global query base for this wave
  const int b = qg >> 12;
  const int i0 = qg & (S - 1);                   // within-batch row base
  const int c15 = lane & 15;
  const int g = lane >> 4;

  // ---- Q fragments in regs (16 k-steps x 8 bf16) ----
  short8 qf[16];
  {
    const u16* qrow = Qb + (size_t)(qg + c15) * D2 + g * 8;
    #pragma unroll
    for (int s = 0; s < 16; ++s) qf[s] = *(const short8*)(qrow + s * 32);
  }

  // ---- QK^T: 5 key blocks x 16 MFMA ----
  f32x4 sc[5];
  const u16* kbat = Kb + (((size_t)b) << 12) * D2;
  #pragma unroll
  for (int t = 0; t < 5; ++t) {
    f32x4 c = {0.f, 0.f, 0.f, 0.f};
    // negative rows (only possible near batch 0 start) read earlier ws regions: safe, masked below
    const u16* krow = kbat + (ptrdiff_t)(i0 - 64 + 16 * t + c15) * D2 + g * 8;
    #pragma unroll
    for (int s = 0; s < 16; ++s) {
      short8 bf = *(const short8*)(krow + s * 32);
      c = __builtin_amdgcn_mfma_f32_16x16x32_bf16(qf[s], bf, c, 0, 0, 0);
    }
    sc[t] = c;
  }

  // ---- mask + scale. C layout: col=lane&15 (key), row=4*(lane>>4)+r (query m)
  float sv[5][4];
  #pragma unroll
  for (int t = 0; t < 5; ++t)
    #pragma unroll
    for (int r = 0; r < 4; ++r) {
      const int m = 4 * g + r;
      const int rel = 16 * t + c15 - m;            // j - (i-64), valid in [0,64)
      const int j = i0 - 64 + 16 * t + c15;        // within-batch key index
      const bool ok = (rel >= 0) && (rel < 64) && (j >= 0);
      sv[t][r] = ok ? sc[t][r] * SCALE : -INFINITY;
    }

  // ---- softmax per query row (16-lane group reduce) ----
  float p[5][4];
  #pragma unroll
  for (int r = 0; r < 4; ++r) {
    float mx = sv[0][r];
    #pragma unroll
    for (int t = 1; t < 5; ++t) mx = fmaxf(mx, sv[t][r]);
    #pragma unroll
    for (int off = 8; off; off >>= 1) mx = fmaxf(mx, __shfl_xor(mx, off));
    float e[5], sum = 0.f;
    #pragma unroll
    for (int t = 0; t < 5; ++t) {
      e[t] = (sv[t][r] == -INFINITY) ? 0.f : __expf(sv[t][r] - mx);
      sum += e[t];
    }
    #pragma unroll
    for (int off = 8; off; off >>= 1) sum += __shfl_xor(sum, off);
    const float rinv = (sum > 0.f) ? 1.f / sum : 0.f;
    #pragma unroll
    for (int t = 0; t < 5; ++t) p[t][r] = e[t] * rinv;
  }

  // ---- stash P (wave-private slices; no barrier needed) ----
  #pragma unroll
  for (int t = 0; t < 5; ++t)
    #pragma unroll
    for (int r = 0; r < 4; ++r) {
      p_jm[w][16 * t + c15][4 * g + r] = p[t][r];
      p_mj[w][4 * g + r][16 * t + c15] = p[t][r];
    }

  // ---- attn rows: zeros + band, nontemporal (issue early, drain under PV) ----
  const fv4 z4 = {0.f, 0.f, 0.f, 0.f};
  #pragma unroll 1
  for (int m = 0; m < 16; ++m) {
    const int i = i0 + m;
    float* arow = out + RET_ELEMS + (size_t)(qg + m) * S;
    #pragma unroll 1
    for (int t2 = 0; t2 < 16; ++t2) {
      const int c0w = t2 * 256;
      float* dst = arow + c0w + lane * 4;
      if ((i - 1 >= c0w) && (i - 64 <= c0w + 255)) {   // wave-uniform
        fv4 v;
        #pragma unroll
        for (int c = 0; c < 4; ++c) {
          const int col = c0w + lane * 4 + c;
          const int rel = col - (i - 64);
          v[c] = (rel >= 0 && rel < 64) ? p_mj[w][m][rel + m] : 0.f;
        }
        __builtin_nontemporal_store(v, (fv4*)dst);
      } else {
        __builtin_nontemporal_store(z4, (fv4*)dst);
      }
    }
  }

  // ---- PV: retrieved[q,:] = sum_j p[q,j] * X[j,:], lane owns 8 d-elems ----
  f32x2 acc[16][4];
  #pragma unroll
  for (int m = 0; m < 16; ++m)
    #pragma unroll
    for (int d = 0; d < 4; ++d) acc[m][d] = (f32x2){0.f, 0.f};

  const int jstart = (i0 >= 64) ? 0 : (64 - i0);
  const u16* xbat = Xb + (((size_t)b) << 12) * D2;
  #pragma unroll 1
  for (int j = jstart; j < 79; ++j) {
    const uint4 xr = *(const uint4*)(xbat + (size_t)(i0 - 64 + j) * D2 + lane * 8);
    f32x2 xv[4];
    xv[0] = (f32x2){bflo(xr.x), bfhi(xr.x)};
    xv[1] = (f32x2){bflo(xr.y), bfhi(xr.y)};
    xv[2] = (f32x2){bflo(xr.z), bfhi(xr.z)};
    xv[3] = (f32x2){bflo(xr.w), bfhi(xr.w)};
    float pall[16];
    *(float4*)&pall[0]  = *(const float4*)&p_jm[w][j][0];
    *(float4*)&pall[4]  = *(const float4*)&p_jm[w][j][4];
    *(float4*)&pall[8]  = *(const float4*)&p_jm[w][j][8];
    *(float4*)&pall[12] = *(const float4*)&p_jm[w][j][12];
    #pragma unroll
    for (int m = 0; m < 16; ++m) {
      const f32x2 pp = (f32x2){pall[m], pall[m]};
      #pragma unroll
      for (int d = 0; d < 4; ++d) acc[m][d] += pp * xv[d];
    }
  }

  #pragma unroll 1
  for (int m = 0; m < 16; ++m) {
    float* rr = out + (size_t)(qg + m) * D2 + lane * 8;
    fv4 r0 = {acc[m][0].x, acc[m][0].y, acc[m][1].x, acc[m][1].y};
    fv4 r1 = {acc[m][2].x, acc[m][2].y, acc[m][3].x, acc[m][3].y};
    __builtin_nontemporal_store(r0, (fv4*)rr);
    __builtin_nontemporal_store(r1, (fv4*)(rr + 4));
  }
}

extern "C" void kernel_launch(void* const* d_in, const int* in_sizes, int n_in,
                              void* d_out, int out_size, void* d_ws, size_t ws_size,
                              hipStream_t stream) {
  const float* states = (const float*)d_in[0];
  const float* W_q    = (const float*)d_in[1];
  const float* W_k    = (const float*)d_in[2];
  float* out = (float*)d_out;

  char* ws = (char*)d_ws;
  u16* Xb  = (u16*)(ws);                         // 16 MB
  u16* Qb  = (u16*)(ws + 16777216);              // 16 MB
  u16* Kb  = (u16*)(ws + 33554432);              // 16 MB
  u16* Wqb = (u16*)(ws + 50331648);
  u16* Wkb = (u16*)(ws + 50855936);

  cast_f32_bf16<<<8192, 256, 0, stream>>>(states, Xb, 2097152);
  cast_f32_bf16<<<256, 256, 0, stream>>>(W_q, Wqb, 65536);
  cast_f32_bf16<<<256, 256, 0, stream>>>(W_k, Wkb, 65536);

  qk_gemm<<<dim3(128, 8), 256, 0, stream>>>(Xb, Wqb, Wkb, Qb, Kb);

  attn_kernel<<<256, 256, 0, stream>>>(Qb, Kb, Xb, out);
}

// Round 4
// 160.670 us; speedup vs baseline: 1.3715x; 1.0823x over previous
//
#include <hip/hip_runtime.h>
#include <hip/hip_bf16.h>
#include <cstdint>

typedef uint16_t u16;
typedef __attribute__((ext_vector_type(8))) short short8;
typedef __attribute__((ext_vector_type(4))) float f32x4;
typedef __attribute__((ext_vector_type(2))) float f32x2;
typedef __attribute__((ext_vector_type(4))) float fv4;   // native vec for nontemporal stores

static constexpr int S = 4096;
static constexpr int D2 = 512;
static constexpr size_t RET_ELEMS = 16384ull * 512ull;      // 8,388,608 floats
static constexpr float SCALE = 0.04419417382415922f;        // 512^-0.5

__device__ __forceinline__ u16 f2bf(float f) {
  uint32_t u = __float_as_uint(f);
  u += 0x7fffu + ((u >> 16) & 1u);
  return (u16)(u >> 16);
}

__device__ __forceinline__ float bflo(uint32_t u) { return __uint_as_float(u << 16); }
__device__ __forceinline__ float bfhi(uint32_t u) { return __uint_as_float(u & 0xffff0000u); }

// ---------------- f32 -> bf16 cast ----------------
__global__ void cast_f32_bf16(const float* __restrict__ src, u16* __restrict__ dst, int n4) {
  int idx = blockIdx.x * blockDim.x + threadIdx.x;
  if (idx < n4) {
    float4 v = *(const float4*)(src + (size_t)idx * 4);
    ushort4 o;
    o.x = f2bf(v.x); o.y = f2bf(v.y); o.z = f2bf(v.z); o.w = f2bf(v.w);
    *(ushort4*)(dst + (size_t)idx * 4) = o;
  }
}

// ---------------- Q/K projection GEMM ----------------
#define BM 128
#define BN 128
#define BK 32
#define LDSP 40

__global__ __launch_bounds__(256) void qk_gemm(
    const u16* __restrict__ Xb, const u16* __restrict__ Wqb, const u16* __restrict__ Wkb,
    u16* __restrict__ Qb, u16* __restrict__ Kb) {
  __shared__ u16 Xs[BM * LDSP];
  __shared__ u16 Ws[BN * LDSP];
  const int m0 = blockIdx.x * BM;
  const int sel = blockIdx.y >> 2;
  const int n0 = (blockIdx.y & 3) * BN;
  const u16* __restrict__ Wb = sel ? Wkb : Wqb;
  u16* __restrict__ Cb = sel ? Kb : Qb;

  const int t = threadIdx.x;
  const int lane = t & 63, w = t >> 6;
  const int wm = w >> 1, wn = w & 1;
  const int r16 = lane & 15, kg = lane >> 4;
  const int srow = t >> 2, skcol = (t & 3) * 8;

  f32x4 acc[4][4] = {};

  for (int kt = 0; kt < D2; kt += BK) {
    __syncthreads();
    for (int p = 0; p < 2; ++p) {
      int row = srow + p * 64;
      uint4 va = *(const uint4*)(Xb + (size_t)(m0 + row) * D2 + kt + skcol);
      *(uint4*)(Xs + row * LDSP + skcol) = va;
      uint4 vb = *(const uint4*)(Wb + (size_t)(n0 + row) * D2 + kt + skcol);
      *(uint4*)(Ws + row * LDSP + skcol) = vb;
    }
    __syncthreads();
    short8 a[4], b[4];
    for (int f = 0; f < 4; ++f) {
      a[f] = *(const short8*)(Xs + (wm * 64 + f * 16 + r16) * LDSP + kg * 8);
      b[f] = *(const short8*)(Ws + (wn * 64 + f * 16 + r16) * LDSP + kg * 8);
    }
    for (int fm = 0; fm < 4; ++fm)
      for (int fn = 0; fn < 4; ++fn)
        acc[fm][fn] = __builtin_amdgcn_mfma_f32_16x16x32_bf16(a[fm], b[fn], acc[fm][fn], 0, 0, 0);
  }

  for (int fm = 0; fm < 4; ++fm) {
    int grow = m0 + wm * 64 + fm * 16 + kg * 4;
    for (int fn = 0; fn < 4; ++fn) {
      int gcol = n0 + wn * 64 + fn * 16 + r16;
      for (int r = 0; r < 4; ++r)
        Cb[(size_t)(grow + r) * D2 + gcol] = f2bf(acc[fm][fn][r]);
    }
  }
}

// ---------------- zero fill of attn (non-band float4s only) ----------------
// One block per output row. Writes every float4 EXCEPT those intersecting the
// band [lo, i-1]; attn_kernel writes exactly those. Disjoint -> order-free.
__global__ __launch_bounds__(256) void fill_zero(float* __restrict__ out) {
  const int row = blockIdx.x;               // 0..16383
  const int i = row & (S - 1);
  const int t = threadIdx.x;
  float* arow = out + RET_ELEMS + (size_t)row * S;
  const int lo = (i >= 64) ? (i - 64) : 0;
  const int hi = i - 1;
  const fv4 z = {0.f, 0.f, 0.f, 0.f};
  #pragma unroll
  for (int k = 0; k < 4; ++k) {
    const int c4 = (t + (k << 8)) << 2;     // float col 0..4092 step 4
    const bool band = (i >= 1) && (c4 + 3 >= lo) && (c4 <= hi);
    if (!band) __builtin_nontemporal_store(z, (fv4*)(arow + c4));
  }
}

// ---------------- fused banded attention (MFMA scores, band-only writes) ----
// 256 blocks x 256 threads. Wave = 16 queries; keys [qg-64, qg+15) in 5 tiles.
__global__ __launch_bounds__(256) void attn_kernel(
    const u16* __restrict__ Qb, const u16* __restrict__ Kb, const u16* __restrict__ Xb,
    float* __restrict__ out) {
  __shared__ float p_jm[4][80][16];   // [wave][band col][query m] -> PV broadcast reads
  __shared__ float p_mj[4][16][85];   // [wave][query m][band col] -> band row writes

  const int bid = blockIdx.x;
  const int swz = (bid & 7) * 32 + (bid >> 3);   // XCD-bijective: 32 contiguous blocks/XCD
  const int w = threadIdx.x >> 6;
  const int lane = threadIdx.x & 63;
  const int qg = swz * 64 + w * 16;              // global query base for this wave
  const int b = qg >> 12;
  const int i0 = qg & (S - 1);                   // within-batch row base
  const int c15 = lane & 15;
  const int g = lane >> 4;

  // ---- Q fragments in regs (16 k-steps x 8 bf16) ----
  short8 qf[16];
  {
    const u16* qrow = Qb + (size_t)(qg + c15) * D2 + g * 8;
    #pragma unroll
    for (int s = 0; s < 16; ++s) qf[s] = *(const short8*)(qrow + s * 32);
  }

  // ---- QK^T: 5 key blocks x 16 MFMA ----
  f32x4 sc[5];
  const u16* kbat = Kb + (((size_t)b) << 12) * D2;
  #pragma unroll
  for (int t = 0; t < 5; ++t) {
    f32x4 c = {0.f, 0.f, 0.f, 0.f};
    const u16* krow = kbat + (ptrdiff_t)(i0 - 64 + 16 * t + c15) * D2 + g * 8;
    #pragma unroll
    for (int s = 0; s < 16; ++s) {
      short8 bf = *(const short8*)(krow + s * 32);
      c = __builtin_amdgcn_mfma_f32_16x16x32_bf16(qf[s], bf, c, 0, 0, 0);
    }
    sc[t] = c;
  }

  // ---- mask + scale. C layout: col=lane&15 (key), row=4*(lane>>4)+r (query m)
  float sv[5][4];
  #pragma unroll
  for (int t = 0; t < 5; ++t)
    #pragma unroll
    for (int r = 0; r < 4; ++r) {
      const int m = 4 * g + r;
      const int rel = 16 * t + c15 - m;            // j - (i-64), valid in [0,64)
      const int j = i0 - 64 + 16 * t + c15;        // within-batch key index
      const bool ok = (rel >= 0) && (rel < 64) && (j >= 0);
      sv[t][r] = ok ? sc[t][r] * SCALE : -INFINITY;
    }

  // ---- softmax per query row (16-lane group reduce) ----
  float p[5][4];
  #pragma unroll
  for (int r = 0; r < 4; ++r) {
    float mx = sv[0][r];
    #pragma unroll
    for (int t = 1; t < 5; ++t) mx = fmaxf(mx, sv[t][r]);
    #pragma unroll
    for (int off = 8; off; off >>= 1) mx = fmaxf(mx, __shfl_xor(mx, off));
    float e[5], sum = 0.f;
    #pragma unroll
    for (int t = 0; t < 5; ++t) {
      e[t] = (sv[t][r] == -INFINITY) ? 0.f : __expf(sv[t][r] - mx);
      sum += e[t];
    }
    #pragma unroll
    for (int off = 8; off; off >>= 1) sum += __shfl_xor(sum, off);
    const float rinv = (sum > 0.f) ? 1.f / sum : 0.f;
    #pragma unroll
    for (int t = 0; t < 5; ++t) p[t][r] = e[t] * rinv;
  }

  // ---- stash P (wave-private slices; no barrier needed) ----
  #pragma unroll
  for (int t = 0; t < 5; ++t)
    #pragma unroll
    for (int r = 0; r < 4; ++r) {
      p_jm[w][16 * t + c15][4 * g + r] = p[t][r];
      p_mj[w][4 * g + r][16 * t + c15] = p[t][r];
    }

  // ---- band-only attn writes: float4s intersecting [lo, i-1] ----
  {
    const int m = lane >> 2;                 // row within wave
    const int l4 = lane & 3;
    const int i = i0 + m;
    if (i >= 1) {
      const int lo = (i >= 64) ? (i - 64) : 0;
      const int f0 = lo >> 2, f1 = (i - 1) >> 2;
      float* arow = out + RET_ELEMS + (size_t)(qg + m) * S;
      #pragma unroll
      for (int it = 0; it < 5; ++it) {
        const int f = f0 + l4 + (it << 2);
        if (f <= f1) {
          fv4 v;
          #pragma unroll
          for (int c = 0; c < 4; ++c) {
            const int rw = 4 * f + c - i0 + 64;      // band slot within wave window
            v[c] = (rw >= 0 && rw < 80) ? p_mj[w][m][rw] : 0.f;
          }
          __builtin_nontemporal_store(v, (fv4*)(arow + 4 * f));
        }
      }
    }
  }

  // ---- PV: retrieved[q,:] = sum_j p[q,j] * X[j,:], lane owns 8 d-elems ----
  f32x2 acc[16][4];
  #pragma unroll
  for (int m = 0; m < 16; ++m)
    #pragma unroll
    for (int d = 0; d < 4; ++d) acc[m][d] = (f32x2){0.f, 0.f};

  const int jstart = (i0 >= 64) ? 0 : (64 - i0);
  const u16* xbat = Xb + (((size_t)b) << 12) * D2;
  #pragma unroll 1
  for (int j = jstart; j < 79; ++j) {
    const uint4 xr = *(const uint4*)(xbat + (size_t)(i0 - 64 + j) * D2 + lane * 8);
    f32x2 xv[4];
    xv[0] = (f32x2){bflo(xr.x), bfhi(xr.x)};
    xv[1] = (f32x2){bflo(xr.y), bfhi(xr.y)};
    xv[2] = (f32x2){bflo(xr.z), bfhi(xr.z)};
    xv[3] = (f32x2){bflo(xr.w), bfhi(xr.w)};
    float pall[16];
    *(float4*)&pall[0]  = *(const float4*)&p_jm[w][j][0];
    *(float4*)&pall[4]  = *(const float4*)&p_jm[w][j][4];
    *(float4*)&pall[8]  = *(const float4*)&p_jm[w][j][8];
    *(float4*)&pall[12] = *(const float4*)&p_jm[w][j][12];
    #pragma unroll
    for (int m = 0; m < 16; ++m) {
      const f32x2 pp = (f32x2){pall[m], pall[m]};
      #pragma unroll
      for (int d = 0; d < 4; ++d) acc[m][d] += pp * xv[d];
    }
  }

  #pragma unroll 1
  for (int m = 0; m < 16; ++m) {
    float* rr = out + (size_t)(qg + m) * D2 + lane * 8;
    fv4 r0 = {acc[m][0].x, acc[m][0].y, acc[m][1].x, acc[m][1].y};
    fv4 r1 = {acc[m][2].x, acc[m][2].y, acc[m][3].x, acc[m][3].y};
    __builtin_nontemporal_store(r0, (fv4*)rr);
    __builtin_nontemporal_store(r1, (fv4*)(rr + 4));
  }
}

extern "C" void kernel_launch(void* const* d_in, const int* in_sizes, int n_in,
                              void* d_out, int out_size, void* d_ws, size_t ws_size,
                              hipStream_t stream) {
  const float* states = (const float*)d_in[0];
  const float* W_q    = (const float*)d_in[1];
  const float* W_k    = (const float*)d_in[2];
  float* out = (float*)d_out;

  char* ws = (char*)d_ws;
  u16* Xb  = (u16*)(ws);                         // 16 MB
  u16* Qb  = (u16*)(ws + 16777216);              // 16 MB
  u16* Kb  = (u16*)(ws + 33554432);              // 16 MB
  u16* Wqb = (u16*)(ws + 50331648);
  u16* Wkb = (u16*)(ws + 50855936);

  cast_f32_bf16<<<8192, 256, 0, stream>>>(states, Xb, 2097152);
  cast_f32_bf16<<<256, 256, 0, stream>>>(W_q, Wqb, 65536);
  cast_f32_bf16<<<256, 256, 0, stream>>>(W_k, Wkb, 65536);

  qk_gemm<<<dim3(128, 8), 256, 0, stream>>>(Xb, Wqb, Wkb, Qb, Kb);

  fill_zero<<<16384, 256, 0, stream>>>(out);

  attn_kernel<<<256, 256, 0, stream>>>(Qb, Kb, Xb, out);
}

// Round 5
// 128.330 us; speedup vs baseline: 1.7171x; 1.2520x over previous
//
#include <hip/hip_runtime.h>
#include <hip/hip_bf16.h>
#include <cstdint>

typedef uint16_t u16;
typedef __attribute__((ext_vector_type(8))) short short8;
typedef __attribute__((ext_vector_type(4))) float f32x4;
typedef __attribute__((ext_vector_type(2))) float f32x2;
typedef __attribute__((ext_vector_type(4))) float fv4;

static constexpr int S = 4096;
static constexpr int D2 = 512;
static constexpr size_t RET_ELEMS = 16384ull * 512ull;
static constexpr float SCALE = 0.04419417382415922f;   // 512^-0.5

__device__ __forceinline__ u16 f2bf(float f) {
  uint32_t u = __float_as_uint(f);
  u += 0x7fffu + ((u >> 16) & 1u);
  return (u16)(u >> 16);
}

__device__ __forceinline__ float bflo(uint32_t u) { return __uint_as_float(u << 16); }
__device__ __forceinline__ float bfhi(uint32_t u) { return __uint_as_float(u & 0xffff0000u); }

// ---------------- f32 -> bf16 cast ----------------
__global__ void cast_f32_bf16(const float* __restrict__ src, u16* __restrict__ dst, int n4) {
  int idx = blockIdx.x * blockDim.x + threadIdx.x;
  if (idx < n4) {
    float4 v = *(const float4*)(src + (size_t)idx * 4);
    ushort4 o;
    o.x = f2bf(v.x); o.y = f2bf(v.y); o.z = f2bf(v.z); o.w = f2bf(v.w);
    *(ushort4*)(dst + (size_t)idx * 4) = o;
  }
}

// ---------------- Q/K projection GEMM (unchanged) ----------------
#define BM 128
#define BN 128
#define BK 32
#define LDSP 40

__global__ __launch_bounds__(256) void qk_gemm(
    const u16* __restrict__ Xb, const u16* __restrict__ Wqb, const u16* __restrict__ Wkb,
    u16* __restrict__ Qb, u16* __restrict__ Kb) {
  __shared__ u16 Xs[BM * LDSP];
  __shared__ u16 Ws[BN * LDSP];
  const int m0 = blockIdx.x * BM;
  const int sel = blockIdx.y >> 2;
  const int n0 = (blockIdx.y & 3) * BN;
  const u16* __restrict__ Wb = sel ? Wkb : Wqb;
  u16* __restrict__ Cb = sel ? Kb : Qb;

  const int t = threadIdx.x;
  const int lane = t & 63, w = t >> 6;
  const int wm = w >> 1, wn = w & 1;
  const int r16 = lane & 15, kg = lane >> 4;
  const int srow = t >> 2, skcol = (t & 3) * 8;

  f32x4 acc[4][4] = {};

  for (int kt = 0; kt < D2; kt += BK) {
    __syncthreads();
    for (int p = 0; p < 2; ++p) {
      int row = srow + p * 64;
      uint4 va = *(const uint4*)(Xb + (size_t)(m0 + row) * D2 + kt + skcol);
      *(uint4*)(Xs + row * LDSP + skcol) = va;
      uint4 vb = *(const uint4*)(Wb + (size_t)(n0 + row) * D2 + kt + skcol);
      *(uint4*)(Ws + row * LDSP + skcol) = vb;
    }
    __syncthreads();
    short8 a[4], b[4];
    for (int f = 0; f < 4; ++f) {
      a[f] = *(const short8*)(Xs + (wm * 64 + f * 16 + r16) * LDSP + kg * 8);
      b[f] = *(const short8*)(Ws + (wn * 64 + f * 16 + r16) * LDSP + kg * 8);
    }
    for (int fm = 0; fm < 4; ++fm)
      for (int fn = 0; fn < 4; ++fn)
        acc[fm][fn] = __builtin_amdgcn_mfma_f32_16x16x32_bf16(a[fm], b[fn], acc[fm][fn], 0, 0, 0);
  }

  for (int fm = 0; fm < 4; ++fm) {
    int grow = m0 + wm * 64 + fm * 16 + kg * 4;
    for (int fn = 0; fn < 4; ++fn) {
      int gcol = n0 + wn * 64 + fn * 16 + r16;
      for (int r = 0; r < 4; ++r)
        Cb[(size_t)(grow + r) * D2 + gcol] = f2bf(acc[fm][fn][r]);
    }
  }
}

// ---------------- fused banded attention + zero fill ----------------
// 1024 blocks x 256 threads (4 waves). Block = 16 queries.
// Each wave redundantly computes the 16x80 score tile (no cross-wave sync),
// interleaves nontemporal zero-stores of the block's 16 attn rows with the
// QK^T loop, then: band writes (rows 4w..4w+3), PV over d-chunk [128w,128w+128).
__global__ __launch_bounds__(256, 4) void attn_kernel(
    const u16* __restrict__ Qb, const u16* __restrict__ Kb, const u16* __restrict__ Xb,
    float* __restrict__ out) {
  __shared__ float p_jm[4][80][16];   // [wave][band col][query m], wave-private copies

  const int bid = blockIdx.x;
  const int swz = (bid & 7) * 128 + (bid >> 3);   // XCD-bijective, contiguous per XCD
  const int w = threadIdx.x >> 6;
  const int lane = threadIdx.x & 63;
  const int qg = swz * 16;
  const int b = qg >> 12;
  const int i0 = qg & (S - 1);
  const int c15 = lane & 15;
  const int g = lane >> 4;

  const u16* kbat = Kb + (((size_t)b) << 12) * D2;
  const u16* qptr = Qb + (size_t)(qg + c15) * D2 + g * 8;
  const u16* kptr = kbat + (ptrdiff_t)(i0 - 64 + c15) * D2 + g * 8;
  float* azero = out + RET_ELEMS + (size_t)qg * S;

  // ---- QK^T (s outer, 5 key tiles inner) with interleaved zero-stores ----
  f32x4 sc[5] = {};
  const fv4 z4 = {0.f, 0.f, 0.f, 0.f};
  #pragma unroll 1
  for (int s = 0; s < 16; ++s) {
    short8 qf = *(const short8*)(qptr + s * 32);
    // 4 zero-store rows (one per owned row), f4 index f = s*64 + lane
    #pragma unroll
    for (int r_ = 0; r_ < 4; ++r_) {
      const int rw = 4 * w + r_;
      const int i = i0 + rw;
      const int f = s * 64 + lane;
      const int flo = (i >= 64) ? ((i - 64) >> 2) : 0;
      const bool band = (i >= 1) && (f >= flo) && (f <= ((i - 1) >> 2));
      if (!band)
        __builtin_nontemporal_store(z4, (fv4*)(azero + (size_t)rw * S + 4 * f));
    }
    #pragma unroll
    for (int t = 0; t < 5; ++t) {
      short8 kf = *(const short8*)(kptr + t * (16 * D2) + s * 32);
      sc[t] = __builtin_amdgcn_mfma_f32_16x16x32_bf16(qf, kf, sc[t], 0, 0, 0);
    }
  }

  // ---- mask + scale. C layout: col=lane&15 (key), row=4*(lane>>4)+r (query m)
  float sv[5][4];
  #pragma unroll
  for (int t = 0; t < 5; ++t)
    #pragma unroll
    for (int r = 0; r < 4; ++r) {
      const int m = 4 * g + r;
      const int rel = 16 * t + c15 - m;            // j - (i-64), valid in [0,64)
      const int j = i0 - 64 + 16 * t + c15;
      const bool ok = (rel >= 0) && (rel < 64) && (j >= 0);
      sv[t][r] = ok ? sc[t][r] * SCALE : -INFINITY;
    }

  // ---- softmax per query row (16-lane group reduce) ----
  float p[5][4];
  #pragma unroll
  for (int r = 0; r < 4; ++r) {
    float mx = sv[0][r];
    #pragma unroll
    for (int t = 1; t < 5; ++t) mx = fmaxf(mx, sv[t][r]);
    #pragma unroll
    for (int off = 8; off; off >>= 1) mx = fmaxf(mx, __shfl_xor(mx, off));
    float e[5], sum = 0.f;
    #pragma unroll
    for (int t = 0; t < 5; ++t) {
      e[t] = (sv[t][r] == -INFINITY) ? 0.f : __expf(sv[t][r] - mx);
      sum += e[t];
    }
    #pragma unroll
    for (int off = 8; off; off >>= 1) sum += __shfl_xor(sum, off);
    const float rinv = (sum > 0.f) ? 1.f / sum : 0.f;
    #pragma unroll
    for (int t = 0; t < 5; ++t) p[t][r] = e[t] * rinv;
  }

  // ---- stash P (wave-private copy) ----
  #pragma unroll
  for (int t = 0; t < 5; ++t)
    #pragma unroll
    for (int r = 0; r < 4; ++r)
      p_jm[w][16 * t + c15][4 * g + r] = p[t][r];

  // ---- band writes: wave w writes rows 4w + (lane>>4) ----
  {
    const int m2 = 4 * w + g;
    const int i = i0 + m2;
    if (i >= 1) {
      const int lo = (i >= 64) ? (i - 64) : 0;
      const int f0 = lo >> 2, f1 = (i - 1) >> 2;
      float* arow = azero + (size_t)m2 * S;
      #pragma unroll
      for (int pass = 0; pass < 2; ++pass) {
        const int f = f0 + c15 + 16 * pass;
        if (f <= f1) {
          fv4 v;
          #pragma unroll
          for (int c = 0; c < 4; ++c) {
            const int col = 4 * f + c;
            const bool in = (col >= lo) && (col <= i - 1);
            v[c] = in ? p_jm[w][col - i0 + 64][m2] : 0.f;
          }
          __builtin_nontemporal_store(v, (fv4*)(arow + 4 * f));
        }
      }
    }
  }

  // ---- PV: wave w owns d-cols [128w, 128w+128); lane owns 2 bf16 cols ----
  f32x2 acc[16];
  #pragma unroll
  for (int m = 0; m < 16; ++m) acc[m] = (f32x2){0.f, 0.f};

  const int jstart = (i0 >= 64) ? 0 : (64 - i0);
  const u16* xcol = Xb + (((size_t)b) << 12) * D2 + (ptrdiff_t)(i0 - 64) * D2
                    + w * 128 + lane * 2;
  #pragma unroll 2
  for (int j = jstart; j < 79; ++j) {
    const uint32_t xu = *(const uint32_t*)(xcol + (size_t)j * D2);
    const f32x2 xv = {bflo(xu), bfhi(xu)};
    float pall[16];
    *(float4*)&pall[0]  = *(const float4*)&p_jm[w][j][0];
    *(float4*)&pall[4]  = *(const float4*)&p_jm[w][j][4];
    *(float4*)&pall[8]  = *(const float4*)&p_jm[w][j][8];
    *(float4*)&pall[12] = *(const float4*)&p_jm[w][j][12];
    #pragma unroll
    for (int m = 0; m < 16; ++m)
      acc[m] += (f32x2){pall[m], pall[m]} * xv;
  }

  #pragma unroll
  for (int m = 0; m < 16; ++m) {
    float* rr = out + (size_t)(qg + m) * D2 + w * 128 + lane * 2;
    __builtin_nontemporal_store(acc[m], (f32x2*)rr);
  }
}

extern "C" void kernel_launch(void* const* d_in, const int* in_sizes, int n_in,
                              void* d_out, int out_size, void* d_ws, size_t ws_size,
                              hipStream_t stream) {
  const float* states = (const float*)d_in[0];
  const float* W_q    = (const float*)d_in[1];
  const float* W_k    = (const float*)d_in[2];
  float* out = (float*)d_out;

  char* ws = (char*)d_ws;
  u16* Xb  = (u16*)(ws);                         // 16 MB
  u16* Qb  = (u16*)(ws + 16777216);              // 16 MB
  u16* Kb  = (u16*)(ws + 33554432);              // 16 MB
  u16* Wqb = (u16*)(ws + 50331648);
  u16* Wkb = (u16*)(ws + 50855936);

  cast_f32_bf16<<<8192, 256, 0, stream>>>(states, Xb, 2097152);
  cast_f32_bf16<<<256, 256, 0, stream>>>(W_q, Wqb, 65536);
  cast_f32_bf16<<<256, 256, 0, stream>>>(W_k, Wkb, 65536);

  qk_gemm<<<dim3(128, 8), 256, 0, stream>>>(Xb, Wqb, Wkb, Qb, Kb);

  attn_kernel<<<1024, 256, 0, stream>>>(Qb, Kb, Xb, out);
}